// Round 2
// baseline (40.725 us; speedup 1.0000x reference)
//
#include <hip/hip_runtime.h>

// Chamfer distance, fully deterministic, no atomics, no memsets.
// pts = img_render_points[0]      : 4096 x 2 f32 (slice 0)
// refs = ref_catheter_skeleton[1] : 32768 x 2 f32 (last slice; flip is min/sum-neutral)
// out  = sum_i min_j ||p_i - r_j|| + sum_j min_i ||p_i - r_j||
//
// Inner trick (same expansion as the reference):
//   ||p-r||^2 = ||p||^2 + (||r||^2 - 2 p.r)
// Stage (x, y, ||r||^2) per staged point; track m' = min(||r||^2 - 2 p.r);
// add ||p||^2 once at fold time, sqrt once per point.

constexpr int N_PTS = 4096;
constexpr int M_REF = 32768;

// ---------------- Kernel 1: sliced partial mins (written exactly once) -----
// 1024 blocks x 256 threads, 2 own points per thread, 512 staged others.
//  rows (b <  512): own=pts,  chunk=b&7   (8 x 512 pts),  slice=b>>3  (64 x 512 refs)
//  cols (b >= 512): own=refs, chunk=bb&63 (64 x 512 refs), slice=bb>>6 (8 x 512 pts)
__global__ __launch_bounds__(256) void chamfer_partial_kernel(
    const float2* __restrict__ pts,
    const float2* __restrict__ refs,
    float* __restrict__ rowpart,   // [64][N_PTS]
    float* __restrict__ colpart)   // [8][M_REF]
{
    __shared__ float4 sh[512];     // (x, y, n2, pad) per staged point, 8 KB
    const int tid = threadIdx.x;
    const int b   = blockIdx.x;

    const float2* own; const float2* oth; float* part;
    int ownBase, othBase;
    if (b < 512) {
        own = pts;  oth = refs;
        ownBase = (b & 7) * 512;
        othBase = (b >> 3) * 512;
        part = rowpart + (b >> 3) * N_PTS + ownBase;
    } else {
        const int bb = b - 512;
        own = refs; oth = pts;
        ownBase = (bb & 63) * 512;
        othBase = (bb >> 6) * 512;
        part = colpart + (bb >> 6) * M_REF + ownBase;
    }

    // Stage 512 other-side points with precomputed squared norms.
    {
        const float2 a = oth[othBase + tid];
        const float2 c = oth[othBase + tid + 256];
        sh[tid]       = make_float4(a.x, a.y, fmaf(a.x, a.x, a.y * a.y), 0.f);
        sh[tid + 256] = make_float4(c.x, c.y, fmaf(c.x, c.x, c.y * c.y), 0.f);
    }
    __syncthreads();

    // Two own points per thread (one float4 load).
    const float4 pp = ((const float4*)(own + ownBase))[tid];
    const float p0x = pp.x, p0y = pp.y, p1x = pp.z, p1y = pp.w;
    float m0 = 3.0e38f, m1 = 3.0e38f;

    #pragma unroll 4
    for (int j = 0; j < 512; j += 2) {
        const float4 r0 = sh[j];       // broadcast reads, conflict-free
        const float4 r1 = sh[j + 1];
        float s;
        s = fmaf(p0y, r0.y, p0x * r0.x); const float d00 = fmaf(-2.f, s, r0.z);
        s = fmaf(p0y, r1.y, p0x * r1.x); const float d01 = fmaf(-2.f, s, r1.z);
        s = fmaf(p1y, r0.y, p1x * r0.x); const float d10 = fmaf(-2.f, s, r0.z);
        s = fmaf(p1y, r1.y, p1x * r1.x); const float d11 = fmaf(-2.f, s, r1.z);
        m0 = fminf(fminf(m0, d00), d01);   // hopefully v_min3_f32
        m1 = fminf(fminf(m1, d10), d11);
    }
    ((float2*)part)[tid] = make_float2(m0, m1);  // written exactly once: no init needed
}

// ---------------- Kernel 2: fold slices, sqrt, per-block sums --------------
// 144 blocks x 256: blocks 0..15 -> pts (4096), blocks 16..143 -> refs (32768)
__global__ __launch_bounds__(256) void chamfer_fold_kernel(
    const float2* __restrict__ pts,
    const float2* __restrict__ refs,
    const float* __restrict__ rowpart,
    const float* __restrict__ colpart,
    float* __restrict__ blocksum)   // [144]
{
    __shared__ float ssum[4];
    const int tid = threadIdx.x;
    const int b   = blockIdx.x;
    float d;
    if (b < 16) {
        const int pt = b * 256 + tid;
        float m = 3.0e38f;
        #pragma unroll
        for (int s = 0; s < 64; ++s) m = fminf(m, rowpart[s * N_PTS + pt]);
        const float2 p = pts[pt];
        d = sqrtf(fmaxf(m + fmaf(p.x, p.x, p.y * p.y), 1e-12f));
    } else {
        const int idx = (b - 16) * 256 + tid;
        float m = 3.0e38f;
        #pragma unroll
        for (int s = 0; s < 8; ++s) m = fminf(m, colpart[s * M_REF + idx]);
        const float2 r = refs[idx];
        d = sqrtf(fmaxf(m + fmaf(r.x, r.x, r.y * r.y), 1e-12f));
    }
    #pragma unroll
    for (int off = 32; off > 0; off >>= 1) d += __shfl_down(d, off, 64);
    const int lane = tid & 63, wave = tid >> 6;
    if (lane == 0) ssum[wave] = d;
    __syncthreads();
    if (tid == 0) blocksum[b] = ssum[0] + ssum[1] + ssum[2] + ssum[3];
}

// ---------------- Kernel 3: final sum (plain store, no atomics) ------------
__global__ __launch_bounds__(256) void chamfer_final_kernel(
    const float* __restrict__ blocksum, float* __restrict__ out)
{
    __shared__ float ssum[4];
    const int tid = threadIdx.x;
    float d = (tid < 144) ? blocksum[tid] : 0.f;
    #pragma unroll
    for (int off = 32; off > 0; off >>= 1) d += __shfl_down(d, off, 64);
    const int lane = tid & 63, wave = tid >> 6;
    if (lane == 0) ssum[wave] = d;
    __syncthreads();
    if (tid == 0) out[0] = ssum[0] + ssum[1] + ssum[2] + ssum[3];
}

extern "C" void kernel_launch(void* const* d_in, const int* in_sizes, int n_in,
                              void* d_out, int out_size, void* d_ws, size_t ws_size,
                              hipStream_t stream) {
    const float2* pts  = (const float2*)d_in[0];            // circle 0 (offset 0)
    const float2* refs = ((const float2*)d_in[1]) + M_REF;  // last (=2nd) skeleton slice

    float* rowpart  = (float*)d_ws;                         // 64*4096  = 262144 floats
    float* colpart  = rowpart + 64 * N_PTS;                 //  8*32768 = 262144 floats
    float* blocksum = colpart + 8 * M_REF;                  // 144 floats
    float* out = (float*)d_out;

    chamfer_partial_kernel<<<1024, 256, 0, stream>>>(pts, refs, rowpart, colpart);
    chamfer_fold_kernel<<<144, 256, 0, stream>>>(pts, refs, rowpart, colpart, blocksum);
    chamfer_final_kernel<<<1, 256, 0, stream>>>(blocksum, out);
}